// Round 9
// baseline (254.430 us; speedup 1.0000x reference)
//
#include <hip/hip_runtime.h>
#include <stdint.h>

#define NN 100000
#define NE 1600000
#define NB 391          // buckets of 256 nodes: bucket = dst >> 8

using u16 = unsigned short;
using u32 = unsigned int;

typedef __attribute__((ext_vector_type(8))) short bf16x8;
typedef __attribute__((ext_vector_type(4))) float f32x4;

__device__ inline u16 f2b(float f){
  u32 u = __float_as_uint(f);
  u32 r = (u + 0x7fffu + ((u >> 16) & 1u)) >> 16;
  return (u16)r;
}

// pack 8 consecutive floats (two float4) into a bf16x8 fragment
__device__ inline bf16x8 cvt8(const float* __restrict__ p){
  float4 a = *(const float4*)p;
  float4 b = *(const float4*)(p + 4);
  union { u32 w[4]; bf16x8 v; } u;
  u.w[0] = (u32)f2b(a.x) | ((u32)f2b(a.y) << 16);
  u.w[1] = (u32)f2b(a.z) | ((u32)f2b(a.w) << 16);
  u.w[2] = (u32)f2b(b.x) | ((u32)f2b(b.y) << 16);
  u.w[3] = (u32)f2b(b.z) | ((u32)f2b(b.w) << 16);
  return u.v;
}

// ---- weight prep (fp32 -> bf16 transposed [n][k]) + coarse bucket histogram --
// cb must be zeroed (hipMemsetAsync) before this kernel.
__global__ __launch_bounds__(512)
void k_prep(const float* __restrict__ Wp1, const float* __restrict__ Ws1,
            const float* __restrict__ Wn1, const float* __restrict__ Wp2,
            const float* __restrict__ Ws2, const float* __restrict__ Wn2,
            u16* __restrict__ wpT1, u16* __restrict__ wc1T,
            u16* __restrict__ wpT2, u16* __restrict__ wc2T,
            const int* __restrict__ dst, int* __restrict__ cb){
  __shared__ int hcb[NB];
  const int tid = threadIdx.x;
  for (int i = tid; i < NB; i += 512) hcb[i] = 0;
  __syncthreads();
  int e0 = blockIdx.x * 2048 + tid;
  #pragma unroll
  for (int j = 0; j < 4; j++){
    int e = e0 + j * 512;
    if (e < NE) atomicAdd(&hcb[dst[e] >> 8], 1);
  }
  // weight conversion (blocks 0..63 cover all ranges)
  int i = blockIdx.x * 512 + tid;
  if (i < 16384){ int n = i >> 7, k = i & 127;
    wpT1[n*128 + k] = f2b(Wp1[k*128 + n]);
    wpT2[n*128 + k] = f2b(Wp2[k*128 + n]);
  }
  if (i < 32768){ int n = i >> 8, k = i & 255;
    float v = (k < 128) ? Ws1[k*128 + n] : Wn1[(k-128)*128 + n];
    wc1T[n*256 + k] = f2b(v);
  }
  if (i < 12288){ int n = i >> 8, k = i & 255;
    float v = 0.f;
    if (n < 40) v = (k < 128) ? Ws2[k*40 + n] : Wn2[(k-128)*40 + n];
    wc2T[n*256 + k] = f2b(v);
  }
  __syncthreads();
  for (int i2 = tid; i2 < NB; i2 += 512)
    if (hcb[i2]) atomicAdd(&cb[i2], hcb[i2]);
}

// exclusive scan of NB (<=512) bucket counts
__global__ __launch_bounds__(512) void k_cb_scan(const int* __restrict__ cb,
                                                 int* __restrict__ cbo,
                                                 int* __restrict__ curB){
  __shared__ int s[512];
  int tid = threadIdx.x;
  int v = (tid < NB) ? cb[tid] : 0;
  s[tid] = v;
  __syncthreads();
  #pragma unroll
  for (int off = 1; off < 512; off <<= 1){
    int t = (tid >= off) ? s[tid - off] : 0;
    __syncthreads();
    s[tid] += t;
    __syncthreads();
  }
  int ex = s[tid] - v;
  if (tid < NB){ cbo[tid] = ex; curB[tid] = ex; }
  if (tid == 511) cbo[NB] = s[511];
}

// pass 1: partition edges into bucket-contiguous regions (LDS-staged so global
// writes are contiguous runs); part stores packed (dstLocal:8 | src:17) u32
__global__ __launch_bounds__(1024) void k_part(const int* __restrict__ src,
                                               const int* __restrict__ dst,
                                               int* __restrict__ curB,
                                               u32* __restrict__ part){
  __shared__ int hist[NB], scn[NB], cur[NB], base[NB];
  __shared__ int2 stage[4096];
  const int tid = threadIdx.x;
  const int e0 = blockIdx.x * 4096;
  const int cnt = min(4096, NE - e0);
  for (int i = tid; i < NB; i += 1024) hist[i] = 0;
  __syncthreads();
  int2 ed[4];
  #pragma unroll
  for (int j = 0; j < 4; j++){
    int e = e0 + j * 1024 + tid;
    if (e < NE){
      ed[j].x = src[e]; ed[j].y = dst[e];
      atomicAdd(&hist[ed[j].y >> 8], 1);
    }
  }
  __syncthreads();
  int hv = (tid < NB) ? hist[tid] : 0;
  if (tid < NB) base[tid] = hv ? atomicAdd(&curB[tid], hv) : 0;
  #pragma unroll
  for (int off = 1; off < 512; off <<= 1){
    int t = 0;
    if (tid < 512 && tid >= off && tid - off < NB) t = hist[tid - off];
    __syncthreads();
    if (tid < NB) hist[tid] += t;
    __syncthreads();
  }
  if (tid < NB){ int ex = hist[tid] - hv; scn[tid] = ex; cur[tid] = ex; }
  __syncthreads();
  #pragma unroll
  for (int j = 0; j < 4; j++){
    int e = e0 + j * 1024 + tid;
    if (e < NE){
      int slot = atomicAdd(&cur[ed[j].y >> 8], 1);
      stage[slot] = ed[j];
    }
  }
  __syncthreads();
  for (int i = tid; i < cnt; i += 1024){
    int2 p = stage[i];
    int b = p.y >> 8;
    part[base[b] + (i - scn[b])] = ((u32)(p.y & 255) << 17) | (u32)p.x;
  }
}

// pass 2: one wg per bucket: per-node histogram+scan -> rp, scatter src ids
__global__ __launch_bounds__(256) void k_bsort(const u32* __restrict__ part,
                                               const int* __restrict__ cbo,
                                               int* __restrict__ rp,
                                               int* __restrict__ esrc){
  __shared__ int cnt[256], sc[256], cur[256];
  const int tid = threadIdx.x;
  const int b = blockIdx.x;
  const int lo = cbo[b], hi = cbo[b + 1];
  cnt[tid] = 0;
  __syncthreads();
  for (int i = lo + tid; i < hi; i += 256)
    atomicAdd(&cnt[part[i] >> 17], 1);
  __syncthreads();
  sc[tid] = cnt[tid];
  __syncthreads();
  #pragma unroll
  for (int off = 1; off < 256; off <<= 1){
    int t = (tid >= off) ? sc[tid - off] : 0;
    __syncthreads();
    sc[tid] += t;
    __syncthreads();
  }
  int ex = sc[tid] - cnt[tid];
  int n = (b << 8) + tid;
  if (n < NN) rp[n] = lo + ex;
  if (b == NB - 1 && tid == 0) rp[NN] = hi;
  cur[tid] = lo + ex;
  __syncthreads();
  for (int i = lo + tid; i < hi; i += 256){
    u32 p = part[i];
    int pos = atomicAdd(&cur[p >> 17], 1);
    esrc[pos] = (int)(p & 0x1FFFFu);
  }
}

// ---------------- segment-max aggregation (one wave per node) ----------------
// post-ReLU messages (>=0): packed-bf16 max == v_pk_max_u16, init 0 handles
// zero-in-degree. Half-wave per row (32x8B), 16 edges in flight per wave.
// At structural floor: FETCH ~177MB = per-XCD compulsory miss traffic.
__global__ void k_agg(const u16* __restrict__ hp, const int* __restrict__ rp,
                      const int* __restrict__ esrc, u16* __restrict__ agg){
  int node = blockIdx.x * 4 + (threadIdx.x >> 6);
  if (node >= NN) return;
  const int lane = threadIdx.x & 63;
  const int half = lane >> 5;
  const int l32  = lane & 31;
  const int lo = rp[node], hi = rp[node + 1];
  u32 m0 = 0, m1 = 0;
  for (int i = lo; i < hi; i += 16){
    int s[8];
    #pragma unroll
    for (int j = 0; j < 8; j++){
      int ii = i + 2 * j + half; if (ii >= hi) ii = hi - 1;
      s[j] = esrc[ii];
    }
    uint2 v[8];
    #pragma unroll
    for (int j = 0; j < 8; j++)
      v[j] = *(const uint2*)&hp[(size_t)s[j] * 128 + l32 * 4];
    #pragma unroll
    for (int j = 0; j < 8; j++){
      asm("v_pk_max_u16 %0, %0, %1" : "+v"(m0) : "v"(v[j].x));
      asm("v_pk_max_u16 %0, %0, %1" : "+v"(m1) : "v"(v[j].y));
    }
  }
  u32 t0 = (u32)__shfl_xor((int)m0, 32);
  u32 t1 = (u32)__shfl_xor((int)m1, 32);
  asm("v_pk_max_u16 %0, %0, %1" : "+v"(m0) : "v"(t0));
  asm("v_pk_max_u16 %0, %0, %1" : "+v"(m1) : "v"(t1));
  if (half == 0)
    *(uint2*)&agg[(size_t)node * 128 + l32 * 4] = make_uint2(m0, m1);
}

// -------- barrier-free MFMA GEMM (K=128): out = A @ Wt^T + bias --------
// W staged in LDS once; K-loop barrier-free, A frags direct from global.
template<int NOUT, int NOUTR, bool A1F32, bool RELU, bool OUTF32>
__global__ __launch_bounds__(512)
void k_dgemm(const void* __restrict__ A1p, const u16* __restrict__ Wt,
             const float* __restrict__ bias, void* __restrict__ outp)
{
  constexpr int K = 128, KP = 136;
  constexpr int NTI = NOUT / 16;
  __shared__ u16 W_lds[NOUT * KP];
  const int tid  = threadIdx.x;
  const int row0 = blockIdx.x * 128;
  const int wave = tid >> 6, lane = tid & 63;
  const int colb = lane & 15;
  const int koff = (lane >> 4) * 8;

  for (int c = tid; c < NOUT * 16; c += 512){
    int n = c >> 4, kc = c & 15;
    *(uint4*)&W_lds[n * KP + kc * 8] = *(const uint4*)&Wt[n * K + kc * 8];
  }
  __syncthreads();

  const int rA = min(row0 + wave * 16 + colb, NN - 1);
  f32x4 acc[NTI] = {};

  #pragma unroll
  for (int k0 = 0; k0 < K; k0 += 64){
    bf16x8 af0, af1;
    if (A1F32){
      const float* A = (const float*)A1p;
      af0 = cvt8(&A[(size_t)rA * 128 + k0 + koff]);
      af1 = cvt8(&A[(size_t)rA * 128 + k0 + 32 + koff]);
    } else {
      const u16* A = (const u16*)A1p;
      af0 = *(const bf16x8*)&A[(size_t)rA * 128 + k0 + koff];
      af1 = *(const bf16x8*)&A[(size_t)rA * 128 + k0 + 32 + koff];
    }
    #pragma unroll
    for (int nt = 0; nt < NTI; nt++){
      const u16* Wr = &W_lds[(nt * 16 + colb) * KP + k0];
      bf16x8 b0 = *(const bf16x8*)&Wr[koff];
      bf16x8 b1 = *(const bf16x8*)&Wr[32 + koff];
      acc[nt] = __builtin_amdgcn_mfma_f32_16x16x32_bf16(af0, b0, acc[nt], 0, 0, 0);
      acc[nt] = __builtin_amdgcn_mfma_f32_16x16x32_bf16(af1, b1, acc[nt], 0, 0, 0);
    }
  }

  const int rowc = wave * 16 + ((lane >> 4) << 2);
  #pragma unroll
  for (int nt = 0; nt < NTI; nt++){
    int col = nt * 16 + colb;
    if (col >= NOUTR) continue;
    float bv = bias[col];
    #pragma unroll
    for (int r = 0; r < 4; r++){
      int gr = row0 + rowc + r;
      if (gr >= NN) continue;
      float v = acc[nt][r] + bv;
      if (RELU) v = fmaxf(v, 0.f);
      if (OUTF32) ((float*)outp)[(size_t)gr * NOUTR + col] = v;
      else        ((u16*)outp)[(size_t)gr * NOUTR + col] = f2b(v);
    }
  }
}

// -------- split-K concat GEMM (K=256): out = [A1|A2] @ Wt^T + bias --------
// W staged in TWO K=128 halves reusing one 34.8KB (NOUT=128) LDS buffer ->
// 4 blocks/CU instead of 2. Phase 0 consumes A1 (fp32 or bf16), phase 1 A2
// (bf16). Accumulator carries across phases; 3 barriers total.
template<int NOUT, int NOUTR, bool A1F32, bool RELU, bool OUTF32>
__global__ __launch_bounds__(512)
void k_cat(const void* __restrict__ A1p, const u16* __restrict__ A2,
           const u16* __restrict__ Wt, const float* __restrict__ bias,
           void* __restrict__ outp)
{
  constexpr int KP = 136;
  constexpr int NTI = NOUT / 16;
  __shared__ u16 W_lds[NOUT * KP];
  const int tid  = threadIdx.x;
  const int row0 = blockIdx.x * 128;
  const int wave = tid >> 6, lane = tid & 63;
  const int colb = lane & 15;
  const int koff = (lane >> 4) * 8;
  const int rA   = min(row0 + wave * 16 + colb, NN - 1);

  f32x4 acc[NTI] = {};

  #pragma unroll
  for (int ph = 0; ph < 2; ph++){
    if (ph) __syncthreads();              // all waves done reading half 0
    for (int c = tid; c < NOUT * 16; c += 512){
      int n = c >> 4, kc = c & 15;
      *(uint4*)&W_lds[n * KP + kc * 8] =
          *(const uint4*)&Wt[n * 256 + ph * 128 + kc * 8];
    }
    __syncthreads();

    #pragma unroll
    for (int k0 = 0; k0 < 128; k0 += 64){
      bf16x8 af0, af1;
      if (ph == 0){
        if (A1F32){
          const float* A = (const float*)A1p;
          af0 = cvt8(&A[(size_t)rA * 128 + k0 + koff]);
          af1 = cvt8(&A[(size_t)rA * 128 + k0 + 32 + koff]);
        } else {
          const u16* A = (const u16*)A1p;
          af0 = *(const bf16x8*)&A[(size_t)rA * 128 + k0 + koff];
          af1 = *(const bf16x8*)&A[(size_t)rA * 128 + k0 + 32 + koff];
        }
      } else {
        af0 = *(const bf16x8*)&A2[(size_t)rA * 128 + k0 + koff];
        af1 = *(const bf16x8*)&A2[(size_t)rA * 128 + k0 + 32 + koff];
      }
      #pragma unroll
      for (int nt = 0; nt < NTI; nt++){
        const u16* Wr = &W_lds[(nt * 16 + colb) * KP + k0];
        bf16x8 b0 = *(const bf16x8*)&Wr[koff];
        bf16x8 b1 = *(const bf16x8*)&Wr[32 + koff];
        acc[nt] = __builtin_amdgcn_mfma_f32_16x16x32_bf16(af0, b0, acc[nt], 0, 0, 0);
        acc[nt] = __builtin_amdgcn_mfma_f32_16x16x32_bf16(af1, b1, acc[nt], 0, 0, 0);
      }
    }
  }

  const int rowc = wave * 16 + ((lane >> 4) << 2);
  #pragma unroll
  for (int nt = 0; nt < NTI; nt++){
    int col = nt * 16 + colb;
    if (col >= NOUTR) continue;
    float bv = bias[col];
    #pragma unroll
    for (int r = 0; r < 4; r++){
      int gr = row0 + rowc + r;
      if (gr >= NN) continue;
      float v = acc[nt][r] + bv;
      if (RELU) v = fmaxf(v, 0.f);
      if (OUTF32) ((float*)outp)[(size_t)gr * NOUTR + col] = v;
      else        ((u16*)outp)[(size_t)gr * NOUTR + col] = f2b(v);
    }
  }
}

// ---------------- host launch ----------------
extern "C" void kernel_launch(void* const* d_in, const int* in_sizes, int n_in,
                              void* d_out, int out_size, void* d_ws, size_t ws_size,
                              hipStream_t stream){
  const float* x   = (const float*)d_in[0];
  const int*   src = (const int*)d_in[1];
  const int*   dst = (const int*)d_in[2];
  const float* Wp1 = (const float*)d_in[3];
  const float* bp1 = (const float*)d_in[4];
  const float* Ws1 = (const float*)d_in[5];
  const float* Wn1 = (const float*)d_in[6];
  const float* b1  = (const float*)d_in[7];
  const float* Wp2 = (const float*)d_in[8];
  const float* bp2 = (const float*)d_in[9];
  const float* Ws2 = (const float*)d_in[10];
  const float* Wn2 = (const float*)d_in[11];
  const float* b2  = (const float*)d_in[12];

  char* ws = (char*)d_ws;
  u16* wpT1 = (u16*)(ws + 0);            // 128x128 bf16
  u16* wc1T = (u16*)(ws + 32768);        // 128x256 bf16
  u16* wpT2 = (u16*)(ws + 98304);        // 128x128 bf16
  u16* wc2T = (u16*)(ws + 131072);       // 48x256 bf16 (cols 40..47 zero)
  int* cb   = (int*)(ws + 155648);       // NB bucket counts
  int* cbo  = (int*)(ws + 157696);       // NB+1 bucket offsets
  int* curB = (int*)(ws + 159744);       // NB reservation cursors
  int* rp   = (int*)(ws + 161792);       // N+1 row pointers
  u32* part = (u32*)(ws + 561920);       // E packed (dstLocal|src), bucket-grouped
  u16* h    = (u16*)(ws + 561920);       // N x 128 bf16 (aliases part; part dead first)
  int* esrc = (int*)(ws + 26161920);     // E src ids sorted by dst (6.4 MB)
  u16* hp   = (u16*)(ws + 32561920);     // N x 128 bf16
  u16* agg  = (u16*)(ws + 58161920);     // N x 128 bf16

  hipMemsetAsync(cb, 0, NB * sizeof(int), stream);
  k_prep<<<(NE + 2047) / 2048, 512, 0, stream>>>(Wp1, Ws1, Wn1, Wp2, Ws2, Wn2,
                                                 wpT1, wc1T, wpT2, wc2T, dst, cb);
  k_cb_scan<<<1, 512, 0, stream>>>(cb, cbo, curB);
  k_part<<<(NE + 4095) / 4096, 1024, 0, stream>>>(src, dst, curB, part);
  k_bsort<<<NB, 256, 0, stream>>>(part, cbo, rp, esrc);

  // layer 1
  k_dgemm<128,128, true ,true ,false>
      <<<(NN + 127) / 128, 512, 0, stream>>>(x, wpT1, bp1, hp);
  k_agg<<<(NN + 3) / 4, 256, 0, stream>>>(hp, rp, esrc, agg);
  k_cat<128,128, true ,true ,false>
      <<<(NN + 127) / 128, 512, 0, stream>>>(x, agg, wc1T, b1, h);
  // layer 2
  k_dgemm<128,128, false,true ,false>
      <<<(NN + 127) / 128, 512, 0, stream>>>(h, wpT2, bp2, hp);
  k_agg<<<(NN + 3) / 4, 256, 0, stream>>>(hp, rp, esrc, agg);
  k_cat< 48, 40, false,false,true >
      <<<(NN + 127) / 128, 512, 0, stream>>>(h, agg, wc2T, b2, d_out);
}

// Round 10
// 243.834 us; speedup vs baseline: 1.0435x; 1.0435x over previous
//
#include <hip/hip_runtime.h>
#include <stdint.h>

#define NN 100000
#define NE 1600000
#define NBK 391         // buckets of 256 nodes: bucket = dst >> 8
#define NPOOL 782       // ceil(NN/128) pool-role blocks
#define NPART 782       // ceil(NE/2048) part-role blocks

using u16 = unsigned short;
using u32 = unsigned int;

typedef __attribute__((ext_vector_type(8))) short bf16x8;
typedef __attribute__((ext_vector_type(4))) float f32x4;

__device__ inline u16 f2b(float f){
  u32 u = __float_as_uint(f);
  u32 r = (u + 0x7fffu + ((u >> 16) & 1u)) >> 16;
  return (u16)r;
}

// pack 8 consecutive floats (two float4) into a bf16x8 fragment
__device__ inline bf16x8 cvt8(const float* __restrict__ p){
  float4 a = *(const float4*)p;
  float4 b = *(const float4*)(p + 4);
  union { u32 w[4]; bf16x8 v; } u;
  u.w[0] = (u32)f2b(a.x) | ((u32)f2b(a.y) << 16);
  u.w[1] = (u32)f2b(a.z) | ((u32)f2b(a.w) << 16);
  u.w[2] = (u32)f2b(b.x) | ((u32)f2b(b.y) << 16);
  u.w[3] = (u32)f2b(b.z) | ((u32)f2b(b.w) << 16);
  return u.v;
}

// ---- weight prep (fp32 -> bf16 transposed [n][k]) + coarse bucket histogram --
// cb and curB must be zeroed (hipMemsetAsync) before this kernel.
__global__ __launch_bounds__(512)
void k_prep(const float* __restrict__ Wp1, const float* __restrict__ Ws1,
            const float* __restrict__ Wn1, const float* __restrict__ Wp2,
            const float* __restrict__ Ws2, const float* __restrict__ Wn2,
            u16* __restrict__ wpT1, u16* __restrict__ wc1T,
            u16* __restrict__ wpT2, u16* __restrict__ wc2T,
            const int* __restrict__ dst, int* __restrict__ cb){
  __shared__ int hcb[NBK];
  const int tid = threadIdx.x;
  for (int i = tid; i < NBK; i += 512) hcb[i] = 0;
  __syncthreads();
  int e0 = blockIdx.x * 2048 + tid;
  #pragma unroll
  for (int j = 0; j < 4; j++){
    int e = e0 + j * 512;
    if (e < NE) atomicAdd(&hcb[dst[e] >> 8], 1);
  }
  int i = blockIdx.x * 512 + tid;
  if (i < 16384){ int n = i >> 7, k = i & 127;
    wpT1[n*128 + k] = f2b(Wp1[k*128 + n]);
    wpT2[n*128 + k] = f2b(Wp2[k*128 + n]);
  }
  if (i < 32768){ int n = i >> 8, k = i & 255;
    float v = (k < 128) ? Ws1[k*128 + n] : Wn1[(k-128)*128 + n];
    wc1T[n*256 + k] = f2b(v);
  }
  if (i < 12288){ int n = i >> 8, k = i & 255;
    float v = 0.f;
    if (n < 40) v = (k < 128) ? Ws2[k*40 + n] : Wn2[(k-128)*40 + n];
    wc2T[n*256 + k] = f2b(v);
  }
  __syncthreads();
  for (int i2 = tid; i2 < NBK; i2 += 512)
    if (hcb[i2]) atomicAdd(&cb[i2], hcb[i2]);
}

// ---- fused pool1 + edge-partition kernel (independent DAG branches) ----
// blocks [0,NPOOL): hp = relu(x @ wpT1^T + bp1)   (barrier-free MFMA GEMM)
// blocks [NPOOL,NPOOL+NPART): partition 2048 edges into bucket-contiguous
//   regions of part[] (packed dstLocal:8|src:17). Bucket bases derived from a
//   block-local exclusive scan of cb; chunk reservation via curB (zero-init).
__global__ __launch_bounds__(512)
void k_pp(const float* __restrict__ x, const u16* __restrict__ wpT1,
          const float* __restrict__ bp1, u16* __restrict__ hp,
          const int* __restrict__ src, const int* __restrict__ dst,
          const int* __restrict__ cb, int* __restrict__ curB,
          u32* __restrict__ part){
  __shared__ __align__(16) char smem[34816];
  const int tid = threadIdx.x;
  if (blockIdx.x < NPOOL){
    // ---------------- pool role ----------------
    u16* W_lds = (u16*)smem;                  // 128 x 136
    const int row0 = blockIdx.x * 128;
    const int wave = tid >> 6, lane = tid & 63;
    const int colb = lane & 15;
    const int koff = (lane >> 4) * 8;
    for (int c = tid; c < 128 * 16; c += 512){
      int n = c >> 4, kc = c & 15;
      *(uint4*)&W_lds[n * 136 + kc * 8] = *(const uint4*)&wpT1[n * 128 + kc * 8];
    }
    __syncthreads();
    const int rA = min(row0 + wave * 16 + colb, NN - 1);
    f32x4 acc[8] = {};
    #pragma unroll
    for (int k0 = 0; k0 < 128; k0 += 64){
      bf16x8 af0 = cvt8(&x[(size_t)rA * 128 + k0 + koff]);
      bf16x8 af1 = cvt8(&x[(size_t)rA * 128 + k0 + 32 + koff]);
      #pragma unroll
      for (int nt = 0; nt < 8; nt++){
        const u16* Wr = &W_lds[(nt * 16 + colb) * 136 + k0];
        bf16x8 b0 = *(const bf16x8*)&Wr[koff];
        bf16x8 b1 = *(const bf16x8*)&Wr[32 + koff];
        acc[nt] = __builtin_amdgcn_mfma_f32_16x16x32_bf16(af0, b0, acc[nt], 0, 0, 0);
        acc[nt] = __builtin_amdgcn_mfma_f32_16x16x32_bf16(af1, b1, acc[nt], 0, 0, 0);
      }
    }
    const int rowc = wave * 16 + ((lane >> 4) << 2);
    #pragma unroll
    for (int nt = 0; nt < 8; nt++){
      int col = nt * 16 + colb;
      float bv = bp1[col];
      #pragma unroll
      for (int r = 0; r < 4; r++){
        int gr = row0 + rowc + r;
        if (gr < NN)
          hp[(size_t)gr * 128 + col] = f2b(fmaxf(acc[nt][r] + bv, 0.f));
      }
    }
  } else {
    // ---------------- part role ----------------
    int* hist = (int*)smem;                   // NBK
    int* scn  = hist + NBK;                   // NBK (local excl scan)
    int* cur  = scn  + NBK;                   // NBK
    int* base = cur  + NBK;                   // NBK (global dest base)
    int2* stage = (int2*)(base + NBK);        // 2048 pairs (also s512 scratch)
    int* s512 = (int*)stage;
    const int e0 = (blockIdx.x - NPOOL) * 2048;
    const int cnt = min(2048, NE - e0);
    for (int i = tid; i < NBK; i += 512) hist[i] = 0;
    __syncthreads();
    int2 ed[4];
    #pragma unroll
    for (int j = 0; j < 4; j++){
      int e = e0 + j * 512 + tid;
      if (e < NE){
        ed[j].x = src[e]; ed[j].y = dst[e];
        atomicAdd(&hist[ed[j].y >> 8], 1);
      }
    }
    __syncthreads();
    // global bucket bases: exclusive scan of cb (block-local recompute)
    int cv = (tid < NBK) ? cb[tid] : 0;
    s512[tid] = cv;
    __syncthreads();
    #pragma unroll
    for (int off = 1; off < 512; off <<= 1){
      int t = (tid >= off) ? s512[tid - off] : 0;
      __syncthreads();
      s512[tid] += t;
      __syncthreads();
    }
    int gex = s512[tid] - cv;
    int hv = (tid < NBK) ? hist[tid] : 0;
    if (tid < NBK) base[tid] = gex + (hv ? atomicAdd(&curB[tid], hv) : 0);
    __syncthreads();
    // local exclusive scan of hist
    s512[tid] = hv;
    __syncthreads();
    #pragma unroll
    for (int off = 1; off < 512; off <<= 1){
      int t = (tid >= off) ? s512[tid - off] : 0;
      __syncthreads();
      s512[tid] += t;
      __syncthreads();
    }
    if (tid < NBK){ int ex = s512[tid] - hv; scn[tid] = ex; cur[tid] = ex; }
    __syncthreads();   // s512 scratch dead; stage reuses it
    #pragma unroll
    for (int j = 0; j < 4; j++){
      int e = e0 + j * 512 + tid;
      if (e < NE){
        int slot = atomicAdd(&cur[ed[j].y >> 8], 1);
        stage[slot] = ed[j];
      }
    }
    __syncthreads();
    for (int i = tid; i < cnt; i += 512){
      int2 p = stage[i];
      int b = p.y >> 8;
      part[base[b] + (i - scn[b])] = ((u32)(p.y & 255) << 17) | (u32)p.x;
    }
  }
}

// ---- bucket sort: one wg per bucket -> rp + esrc (lo/hi from local cb scan) --
__global__ __launch_bounds__(512) void k_bsort(const u32* __restrict__ part,
                                               const int* __restrict__ cb,
                                               int* __restrict__ rp,
                                               int* __restrict__ esrc){
  __shared__ int s512[512];
  __shared__ int cnt[256], sc[256], cur[256];
  __shared__ int lohi[2];
  const int tid = threadIdx.x;
  const int b = blockIdx.x;
  int cv = (tid < NBK) ? cb[tid] : 0;
  s512[tid] = cv;
  __syncthreads();
  #pragma unroll
  for (int off = 1; off < 512; off <<= 1){
    int t = (tid >= off) ? s512[tid - off] : 0;
    __syncthreads();
    s512[tid] += t;
    __syncthreads();
  }
  if (tid == b){ lohi[0] = s512[tid] - cv; lohi[1] = s512[tid]; }
  if (tid < 256) cnt[tid] = 0;
  __syncthreads();
  const int lo = lohi[0], hi = lohi[1];
  for (int i = lo + tid; i < hi; i += 512)
    atomicAdd(&cnt[part[i] >> 17], 1);
  __syncthreads();
  if (tid < 256) sc[tid] = cnt[tid];
  __syncthreads();
  #pragma unroll
  for (int off = 1; off < 256; off <<= 1){
    int t = (tid < 256 && tid >= off) ? sc[tid - off] : 0;
    __syncthreads();
    if (tid < 256) sc[tid] += t;
    __syncthreads();
  }
  if (tid < 256){
    int ex = sc[tid] - cnt[tid];
    int n = (b << 8) + tid;
    if (n < NN) rp[n] = lo + ex;
    cur[tid] = lo + ex;
  }
  if (b == NBK - 1 && tid == 0) rp[NN] = hi;
  __syncthreads();
  for (int i = lo + tid; i < hi; i += 512){
    u32 p = part[i];
    int pos = atomicAdd(&cur[p >> 17], 1);
    esrc[pos] = (int)(p & 0x1FFFFu);
  }
}

// ---------------- segment-max aggregation (one wave per node) ----------------
// post-ReLU messages (>=0): packed-bf16 max == v_pk_max_u16, init 0 handles
// zero-in-degree. Half-wave per row (32x8B), 16 edges in flight per wave.
// Structural floor: FETCH ~177MB = per-XCD compulsory row traffic at the
// fabric's ~3.6TB/s random-256B rate (VALU-cut and 2x-in-flight both neutral).
__global__ void k_agg(const u16* __restrict__ hp, const int* __restrict__ rp,
                      const int* __restrict__ esrc, u16* __restrict__ agg){
  int node = blockIdx.x * 4 + (threadIdx.x >> 6);
  if (node >= NN) return;
  const int lane = threadIdx.x & 63;
  const int half = lane >> 5;
  const int l32  = lane & 31;
  const int lo = rp[node], hi = rp[node + 1];
  u32 m0 = 0, m1 = 0;
  for (int i = lo; i < hi; i += 16){
    int s[8];
    #pragma unroll
    for (int j = 0; j < 8; j++){
      int ii = i + 2 * j + half; if (ii >= hi) ii = hi - 1;
      s[j] = esrc[ii];
    }
    uint2 v[8];
    #pragma unroll
    for (int j = 0; j < 8; j++)
      v[j] = *(const uint2*)&hp[(size_t)s[j] * 128 + l32 * 4];
    #pragma unroll
    for (int j = 0; j < 8; j++){
      asm("v_pk_max_u16 %0, %0, %1" : "+v"(m0) : "v"(v[j].x));
      asm("v_pk_max_u16 %0, %0, %1" : "+v"(m1) : "v"(v[j].y));
    }
  }
  u32 t0 = (u32)__shfl_xor((int)m0, 32);
  u32 t1 = (u32)__shfl_xor((int)m1, 32);
  asm("v_pk_max_u16 %0, %0, %1" : "+v"(m0) : "v"(t0));
  asm("v_pk_max_u16 %0, %0, %1" : "+v"(m1) : "v"(t1));
  if (half == 0)
    *(uint2*)&agg[(size_t)node * 128 + l32 * 4] = make_uint2(m0, m1);
}

// -------- barrier-free MFMA GEMM: out = [A1|A2] @ Wt^T + bias --------
// (round-8 monolithic config — best measured). W staged once; K-loop
// barrier-free; A frags direct from global (rows clamp to NN-1).
template<int K, int NOUT, int NOUTR, bool A1F32, bool HASA2, bool RELU, bool OUTF32>
__global__ __launch_bounds__(512)
void k_dgemm(const void* __restrict__ A1p, const u16* __restrict__ A2,
             const u16* __restrict__ Wt, const float* __restrict__ bias,
             void* __restrict__ outp)
{
  constexpr int KP  = K + 8;
  constexpr int NTI = NOUT / 16;
  __shared__ u16 W_lds[NOUT * KP];
  const int tid  = threadIdx.x;
  const int row0 = blockIdx.x * 128;
  const int wave = tid >> 6, lane = tid & 63;
  const int colb = lane & 15;
  const int koff = (lane >> 4) * 8;

  for (int c = tid; c < NOUT * (K / 8); c += 512){
    int n = c / (K / 8), kc = c % (K / 8);
    *(uint4*)&W_lds[n * KP + kc * 8] = *(const uint4*)&Wt[n * K + kc * 8];
  }
  __syncthreads();

  const int rA = min(row0 + wave * 16 + colb, NN - 1);
  f32x4 acc[NTI] = {};

  #pragma unroll
  for (int k0 = 0; k0 < K; k0 += 64){
    bf16x8 af0, af1;
    if (A1F32 && k0 < 128){
      const float* A = (const float*)A1p;
      af0 = cvt8(&A[(size_t)rA * 128 + k0 + koff]);
      af1 = cvt8(&A[(size_t)rA * 128 + k0 + 32 + koff]);
    } else {
      const u16* A = (HASA2 && k0 >= 128) ? A2 : (const u16*)A1p;
      int kb = (HASA2 && k0 >= 128) ? (k0 - 128) : k0;
      af0 = *(const bf16x8*)&A[(size_t)rA * 128 + kb + koff];
      af1 = *(const bf16x8*)&A[(size_t)rA * 128 + kb + 32 + koff];
    }
    #pragma unroll
    for (int nt = 0; nt < NTI; nt++){
      const u16* Wr = &W_lds[(nt * 16 + colb) * KP + k0];
      bf16x8 b0 = *(const bf16x8*)&Wr[koff];
      bf16x8 b1 = *(const bf16x8*)&Wr[32 + koff];
      acc[nt] = __builtin_amdgcn_mfma_f32_16x16x32_bf16(af0, b0, acc[nt], 0, 0, 0);
      acc[nt] = __builtin_amdgcn_mfma_f32_16x16x32_bf16(af1, b1, acc[nt], 0, 0, 0);
    }
  }

  const int rowc = wave * 16 + ((lane >> 4) << 2);
  #pragma unroll
  for (int nt = 0; nt < NTI; nt++){
    int col = nt * 16 + colb;
    if (col >= NOUTR) continue;
    float bv = bias[col];
    #pragma unroll
    for (int r = 0; r < 4; r++){
      int gr = row0 + rowc + r;
      if (gr >= NN) continue;
      float v = acc[nt][r] + bv;
      if (RELU) v = fmaxf(v, 0.f);
      if (OUTF32) ((float*)outp)[(size_t)gr * NOUTR + col] = v;
      else        ((u16*)outp)[(size_t)gr * NOUTR + col] = f2b(v);
    }
  }
}

// ---------------- host launch ----------------
extern "C" void kernel_launch(void* const* d_in, const int* in_sizes, int n_in,
                              void* d_out, int out_size, void* d_ws, size_t ws_size,
                              hipStream_t stream){
  const float* x   = (const float*)d_in[0];
  const int*   src = (const int*)d_in[1];
  const int*   dst = (const int*)d_in[2];
  const float* Wp1 = (const float*)d_in[3];
  const float* bp1 = (const float*)d_in[4];
  const float* Ws1 = (const float*)d_in[5];
  const float* Wn1 = (const float*)d_in[6];
  const float* b1  = (const float*)d_in[7];
  const float* Wp2 = (const float*)d_in[8];
  const float* bp2 = (const float*)d_in[9];
  const float* Ws2 = (const float*)d_in[10];
  const float* Wn2 = (const float*)d_in[11];
  const float* b2  = (const float*)d_in[12];

  char* ws = (char*)d_ws;
  u16* wpT1 = (u16*)(ws + 0);            // 128x128 bf16
  u16* wc1T = (u16*)(ws + 32768);        // 128x256 bf16
  u16* wpT2 = (u16*)(ws + 98304);        // 128x128 bf16
  u16* wc2T = (u16*)(ws + 131072);       // 48x256 bf16 (cols 40..47 zero)
  int* cb   = (int*)(ws + 155648);       // NBK bucket counts
  int* curB = (int*)(ws + 157696);       // NBK reservation cursors (0-based)
  int* rp   = (int*)(ws + 161792);       // N+1 row pointers
  u32* part = (u32*)(ws + 561920);       // E packed (dstLocal|src), bucket-grouped
  u16* h    = (u16*)(ws + 561920);       // N x 128 bf16 (aliases part; part dead first)
  int* esrc = (int*)(ws + 26161920);     // E src ids sorted by dst (6.4 MB)
  u16* hp   = (u16*)(ws + 32561920);     // N x 128 bf16
  u16* agg  = (u16*)(ws + 58161920);     // N x 128 bf16

  hipMemsetAsync(ws + 155648, 0, 4096, stream);   // cb + curB
  k_prep<<<(NE + 2047) / 2048, 512, 0, stream>>>(Wp1, Ws1, Wn1, Wp2, Ws2, Wn2,
                                                 wpT1, wc1T, wpT2, wc2T, dst, cb);
  // pool1 (hp = relu(x@Wp1+bp1)) runs concurrently with edge partitioning
  k_pp<<<NPOOL + NPART, 512, 0, stream>>>(x, wpT1, bp1, hp, src, dst, cb, curB, part);
  k_bsort<<<NBK, 512, 0, stream>>>(part, cb, rp, esrc);

  // layer 1
  k_agg<<<(NN + 3) / 4, 256, 0, stream>>>(hp, rp, esrc, agg);
  k_dgemm<256,128,128, true ,true ,true ,false>
      <<<(NN + 127) / 128, 512, 0, stream>>>(x, agg, wc1T, b1, h);
  // layer 2
  k_dgemm<128,128,128, false,false,true ,false>
      <<<(NN + 127) / 128, 512, 0, stream>>>(h, nullptr, wpT2, bp2, hp);
  k_agg<<<(NN + 3) / 4, 256, 0, stream>>>(hp, rp, esrc, agg);
  k_dgemm<256, 48, 40, false,true ,false,true >
      <<<(NN + 127) / 128, 512, 0, stream>>>(h, agg, wc2T, b2, d_out);
}